// Round 1
// baseline (503.494 us; speedup 1.0000x reference)
//
#include <hip/hip_runtime.h>
#include <math.h>

#define B 32
#define NBOX 24564
#define NCLS 81
#define ROWLEN 93
#define CONF_T 0.5f
#define IOU_T 0.35f
#define NUM_PRED 10
#define IMG_W 512.0f
#define IMG_H 512.0f

#define BPB 64                                   // boxes per block in decode
#define K1_THREADS 256
#define NBLK ((NBOX + BPB - 1) / BPB)            // 384 blocks per batch item

#define K2_THREADS 1024
#define NPER ((NBOX + K2_THREADS - 1) / K2_THREADS)  // 24 scores per thread

// Kernel 1: per-box class argmax/max + box decode.
// Block = 256 threads handles 64 boxes: stage 64*93 floats into LDS with
// coalesced dword loads, then 4 lanes per box reduce the class argmax.
__global__ __launch_bounds__(K1_THREADS) void decode_kernel(
    const float* __restrict__ y, float4* __restrict__ boxes,
    float* __restrict__ scores, float* __restrict__ clsid)
{
    __shared__ float lds[BPB * ROWLEN];          // 23808 B
    int bid  = blockIdx.x;
    int b    = bid / NBLK;
    int blk  = bid % NBLK;
    int box0 = blk * BPB;
    int nb   = NBOX - box0; if (nb > BPB) nb = BPB;
    int elems = nb * ROWLEN;
    const float* src = y + ((size_t)b * NBOX + box0) * ROWLEN;
    for (int k = threadIdx.x; k < elems; k += K1_THREADS)
        lds[k] = src[k];
    __syncthreads();

    int q  = threadIdx.x & 3;                    // lane-quad within a box
    int bl = threadIdx.x >> 2;                   // local box index
    if (bl >= nb) return;
    const float* row = &lds[bl * ROWLEN];

    // strided partial argmax; strict '>' keeps first occurrence per lane
    float best = -INFINITY; int bci = 0x7fffffff;
    for (int c = q; c < NCLS; c += 4) {
        float v = row[c];
        if (v > best) { best = v; bci = c; }
    }
    // combine the 4 lanes; tie-break by smallest class index (jnp.argmax = first)
    #pragma unroll
    for (int m = 1; m <= 2; m <<= 1) {
        float ov = __shfl_xor(best, m, 64);
        int   oi = __shfl_xor(bci,  m, 64);
        if (ov > best || (ov == best && oi < bci)) { best = ov; bci = oi; }
    }

    if (q == 0) {
        const float* t = row + NCLS;             // [off0..3, acx, acy, aw, ah, v0..v3]
        float off0=t[0], off1=t[1], off2=t[2], off3=t[3];
        float acx =t[4], acy =t[5], aw  =t[6], ah  =t[7];
        float v0  =t[8], v1  =t[9], v2  =t[10], v3 =t[11];
        float cx = off0 * v0 * aw + acx;
        float cy = off1 * v1 * ah + acy;
        float w  = expf(off2 * v2) * aw;
        float h  = expf(off3 * v3) * ah;
        float4 bx;
        bx.x = (cx - 0.5f * w) * IMG_W;
        bx.y = (cy - 0.5f * h) * IMG_H;
        bx.z = (cx + 0.5f * w) * IMG_W;
        bx.w = (cy + 0.5f * h) * IMG_H;
        size_t g = (size_t)b * NBOX + box0 + bl;
        boxes[g] = bx;
        clsid[g] = (float)bci;
        bool valid = (bci != 0) && (best >= CONF_T);
        scores[g] = valid ? best : -INFINITY;
    }
}

// Kernel 2: one block per batch item. Greedy NMS, 10 rounds (= NUM_PRED;
// greedy picks are non-increasing so top_k(kept,10) == first 10 picks).
__global__ __launch_bounds__(K2_THREADS) void nms_kernel(
    const float4* __restrict__ boxes, const float* __restrict__ scores,
    const float* __restrict__ clsid, float* __restrict__ out)
{
    __shared__ float rv[K2_THREADS];
    __shared__ int   ri[K2_THREADS];
    __shared__ float sb[4];
    int b   = blockIdx.x;
    int tid = threadIdx.x;
    const float*  sc_g = scores + (size_t)b * NBOX;
    const float4* bx_g = boxes  + (size_t)b * NBOX;

    float sc[NPER];
    #pragma unroll
    for (int j = 0; j < NPER; j++) {
        int g = j * K2_THREADS + tid;
        sc[j] = (g < NBOX) ? sc_g[g] : -INFINITY;
    }

    for (int r = 0; r < NUM_PRED; r++) {
        // local argmax (ascending g => strict '>' keeps smallest index; ties
        // across threads resolved by explicit index compare)
        float v = -INFINITY; int idx = 0x7fffffff;
        #pragma unroll
        for (int j = 0; j < NPER; j++) {
            int g = j * K2_THREADS + tid;
            if (sc[j] > v || (sc[j] == v && g < idx)) { v = sc[j]; idx = g; }
        }
        rv[tid] = v; ri[tid] = idx;
        __syncthreads();
        for (int s = K2_THREADS / 2; s > 0; s >>= 1) {
            if (tid < s) {
                float ov = rv[tid + s]; int oi = ri[tid + s];
                if (ov > rv[tid] || (ov == rv[tid] && oi < ri[tid])) {
                    rv[tid] = ov; ri[tid] = oi;
                }
            }
            __syncthreads();
        }
        float bv = rv[0]; int bi = ri[0];
        bool ok = (bv > -INFINITY);

        if (tid == 0) {
            float* o = out + ((size_t)b * NUM_PRED + r) * 6;
            if (ok) {
                float4 bb = bx_g[bi];
                sb[0] = bb.x; sb[1] = bb.y; sb[2] = bb.z; sb[3] = bb.w;
                o[0] = clsid[(size_t)b * NBOX + bi];
                o[1] = bv;
                o[2] = bb.x; o[3] = bb.y; o[4] = bb.z; o[5] = bb.w;
            } else {
                for (int k = 0; k < 6; k++) o[k] = 0.0f;
            }
        }
        __syncthreads();

        if (ok) {
            float qx0 = sb[0], qy0 = sb[1], qx1 = sb[2], qy1 = sb[3];
            float aq = (qx1 - qx0) * (qy1 - qy0);
            #pragma unroll
            for (int j = 0; j < NPER; j++) {
                int g = j * K2_THREADS + tid;
                if (g < NBOX && sc[j] > -INFINITY) {
                    float4 p = bx_g[g];
                    float iw = fmaxf(fminf(p.z, qx1) - fmaxf(p.x, qx0), 0.0f);
                    float ih = fmaxf(fminf(p.w, qy1) - fmaxf(p.y, qy0), 0.0f);
                    float inter = iw * ih;
                    float ab = (p.z - p.x) * (p.w - p.y);
                    float iou = inter / (ab + aq - inter + 1e-12f);
                    if (iou > IOU_T) sc[j] = -INFINITY;   // includes best itself
                }
            }
        }
        __syncthreads();
    }
}

extern "C" void kernel_launch(void* const* d_in, const int* in_sizes, int n_in,
                              void* d_out, int out_size, void* d_ws, size_t ws_size,
                              hipStream_t stream) {
    const float* y = (const float*)d_in[0];
    float* out = (float*)d_out;
    float* ws  = (float*)d_ws;
    // workspace layout: boxes (B*NBOX float4, 16B-aligned at base) | scores | clsid
    float4* boxes  = (float4*)ws;
    float*  scores = ws + (size_t)B * NBOX * 4;
    float*  clsidp = scores + (size_t)B * NBOX;

    decode_kernel<<<B * NBLK, K1_THREADS, 0, stream>>>(y, boxes, scores, clsidp);
    nms_kernel<<<B, K2_THREADS, 0, stream>>>(boxes, scores, clsidp, out);
}